// Round 5
// baseline (211.691 us; speedup 1.0000x reference)
//
#include <hip/hip_runtime.h>

// Problem constants (fixed by reference)
#define NB     432               // grid blocks; must all be co-resident (see launch_bounds note)
#define BATCH  2
#define CIN    64
#define COUT   128
#define GD     14                // padded grid dim (12 + 2 halo)
#define GD2    (GD*GD)           // 196
#define NCELL  (GD*GD*GD)        // 2744
#define M      4096              // BATCH*NPTS
#define DCELL  1728              // 12^3 dense cells per batch
#define MAXP   16                // max points per cell tracked (Poisson lambda=1.19; P(>16)~1e-14)

typedef __bf16 bf16x8 __attribute__((ext_vector_type(8)));
typedef float  f32x4  __attribute__((ext_vector_type(4)));
typedef unsigned short us8 __attribute__((ext_vector_type(8)));

__device__ __forceinline__ unsigned short bfc(float f) {
    return __builtin_bit_cast(unsigned short, (__bf16)f);   // RNE f32->bf16
}

// Persistent epoch counter for the grid barrier. Zero at module load; never reset.
// Each launch adds exactly 2*NB (two barriers), so "next multiple of NB" stays aligned
// across graph replays. Same work every call.
__device__ int g_cnt;

__device__ __forceinline__ void grid_barrier(int tid) {
    __syncthreads();   // all waves drain vmcnt before s_barrier -> block's stores are in local L2
    if (tid == 0) {
        __threadfence();   // agent-scope release: write back this XCD's dirty L2
        int old = __hip_atomic_fetch_add(&g_cnt, 1, __ATOMIC_ACQ_REL, __HIP_MEMORY_SCOPE_AGENT);
        int target = (old / NB + 1) * NB;
        while (__hip_atomic_load(&g_cnt, __ATOMIC_ACQUIRE, __HIP_MEMORY_SCOPE_AGENT) < target)
            __builtin_amdgcn_s_sleep(4);
        __threadfence();   // acquire: invalidate this CU's L1 / XCD L2 read path
    }
    __syncthreads();
}

// ONE kernel: zero+transpose | barrier | scatter+bucket | barrier | conv -> out
__global__ __launch_bounds__(256, 2) void k_all(const float* __restrict__ points,
                                                const float* __restrict__ features,
                                                const float* __restrict__ weight,
                                                const float* __restrict__ bias,
                                                float* __restrict__ out,
                                                float* __restrict__ voxgrid,
                                                int* __restrict__ ccount,
                                                int* __restrict__ clist,
                                                unsigned short* __restrict__ wT2) {
    const int t   = threadIdx.x;
    const int bid = blockIdx.x;
    __shared__ unsigned short lds[64*194];   // 24,832 B -> 6 blocks/CU by LDS

    // ---------------- phase 0: zero voxgrid+ccount (354,688 dwords = 88,672 float4) ----------------
    {
        const int i = bid*256 + t;           // 110,592 threads cover 88,672 slots
        if (i < 88672) ((float4*)voxgrid)[i] = make_float4(0.f, 0.f, 0.f, 0.f);
    }
    // ---------------- phase 0b: blocks 0..17 transpose weight -> bf16 wT2[p][n][kk=ok*64+k] --------
    if (bid < 18) {
        const int p  = bid >> 1;             // (oi,oj) pair
        const int nh = bid & 1;              // cout half
        #pragma unroll
        for (int i2 = 0; i2 < 48; ++i2) {    // 12,288 elems, load coalesced over n
            const int s  = t + i2*256;
            const int nn = s & 63;
            const int kk = s >> 6;           // 0..191
            const int ok = kk >> 6, k = kk & 63;
            lds[nn*194 + kk] = bfc(weight[(p*3 + ok)*8192 + k*128 + nh*64 + nn]);
        }
        __syncthreads();
        #pragma unroll
        for (int i2 = 0; i2 < 48; ++i2) {    // store coalesced over kk
            const int s  = t + i2*256;
            const int nn = s / 192;
            const int kk = s - nn*192;
            wT2[(size_t)(p*128 + nh*64 + nn)*192 + kk] = lds[nn*194 + kk];
        }
    }

    grid_barrier(t);

    // ---------------- phase 1: scatter features into voxgrid + build per-cell point lists ----------
    if (bid >= 18) {
        for (int u = bid - 18; u < 1024; u += NB - 18) {   // 1024 units of 256 threads
            const int idx = u*256 + t;                      // [0, M*CIN)
            const int g   = idx >> 6;                       // wave-uniform point index
            const int cin = idx & 63;
            const int vx = (int)points[g*3 + 0];
            const int vy = (int)points[g*3 + 1];
            const int vz = (int)points[g*3 + 2];
            const int b  = g >> 11;
            atomicAdd(&voxgrid[((size_t)b*NCELL + (vx+1)*GD2 + (vy+1)*GD + (vz+1))*CIN + cin],
                      features[idx]);
            if (cin == 0) {
                const int mg   = b*DCELL + vx*144 + vy*12 + vz;
                const int slot = atomicAdd(&ccount[mg], 1);
                if (slot < MAXP) clist[mg*MAXP + slot] = g;
            }
        }
    }

    grid_barrier(t);

    // ---------------- phase 2: dense MFMA conv over 12^3, scatter rows straight to out -------------
    // delta(p)*64 for p = oi*3+oj, base at ok=-1 (contiguous 192-channel span)
    static constexpr int DOFF[9] = { -13504, -12608, -11712,
                                       -960,    -64,    832,
                                      11584,  12480,  13376 };
    const int l   = t & 63;
    const int w   = t >> 6;
    const int q   = l >> 4;                  // k-group / C-row quad
    const int col = l & 15;                  // A m-row and B n-col lane index
    const int mt  = bid >> 1;                // 0..215 m-tile
    const int nh  = bid & 1;
    const int b2  = (mt >= 108);
    const int cil = (mt - b2*108) * 16;
    const int n0  = nh*64 + w*16;

    const int ci = cil + col;
    const int cx = ci/144, cy = (ci/12)%12, cz = ci%12;
    const float* aptr = voxgrid + ((size_t)b2*NCELL + (cx+1)*GD2 + (cy+1)*GD + (cz+1))*CIN + q*8;
    const unsigned short* bptr = wT2 + (size_t)(n0 + col)*192 + q*8;

    f32x4 acc = {0.f, 0.f, 0.f, 0.f};
    float4 A0[4], A1[4]; us8 B0[4];
    #pragma unroll
    for (int st = 0; st < 4; ++st) {         // prolog: panel 0, steps 0..3
        A0[st] = *(const float4*)(aptr + DOFF[0] + st*32);
        A1[st] = *(const float4*)(aptr + DOFF[0] + st*32 + 4);
        B0[st] = *(const us8*)(bptr + st*32);
    }
    #pragma unroll
    for (int st = 0; st < 54; ++st) {        // 9 panels x 6 k-steps of 32
        const int sl = st & 3;
        const float4 xa = A0[sl], xb = A1[sl];
        const us8 bb = B0[sl];
        if (st + 4 < 54) {
            const int p = (st + 4) / 6, s = (st + 4) % 6;
            A0[sl] = *(const float4*)(aptr + DOFF[p] + s*32);
            A1[sl] = *(const float4*)(aptr + DOFF[p] + s*32 + 4);
            B0[sl] = *(const us8*)(bptr + p*24576 + s*32);
        }
        us8 a;
        a[0]=bfc(xa.x); a[1]=bfc(xa.y); a[2]=bfc(xa.z); a[3]=bfc(xa.w);
        a[4]=bfc(xb.x); a[5]=bfc(xb.y); a[6]=bfc(xb.z); a[7]=bfc(xb.w);
        acc = __builtin_amdgcn_mfma_f32_16x16x32_bf16(
                  __builtin_bit_cast(bf16x8, a), __builtin_bit_cast(bf16x8, bb), acc, 0, 0, 0);
    }

    // epilogue: C row m = q*4+r (cell), col n = lane&15 (cout); write each point's row directly
    const float bs = bias[n0 + col];
    #pragma unroll
    for (int r = 0; r < 4; ++r) {
        const int cir = cil + q*4 + r;
        const int mg  = b2*DCELL + cir;
        const int cnt = min(ccount[mg], MAXP);
        for (int j = 0; j < cnt; ++j) {
            const int g = clist[mg*MAXP + j];
            out[(size_t)g*COUT + n0 + col] = acc[r] + bs;
        }
    }
}

extern "C" void kernel_launch(void* const* d_in, const int* in_sizes, int n_in,
                              void* d_out, int out_size, void* d_ws, size_t ws_size,
                              hipStream_t stream) {
    (void)in_sizes; (void)n_in; (void)out_size; (void)ws_size;
    const float* points   = (const float*)d_in[0];  // (2,2048,3)
    const float* features = (const float*)d_in[1];  // (2,2048,64)
    const float* weight   = (const float*)d_in[2];  // (3,3,3,64,128)
    const float* bias     = (const float*)d_in[3];  // (128,)
    float* out = (float*)d_out;                     // (2,2048,128)

    char* ws = (char*)d_ws;
    float*          voxgrid = (float*)ws;                        // 1,404,928 B (zeroed in-kernel)
    int*            ccount  = (int*)(ws + 1404928);              //    13,824 B (zeroed in-kernel, contiguous with voxgrid)
    int*            clist   = (int*)(ws + 1418752);              //   221,184 B (guarded by ccount)
    unsigned short* wT2     = (unsigned short*)(ws + 1639936);   //   442,368 B

    k_all<<<NB, 256, 0, stream>>>(points, features, weight, bias, out,
                                  voxgrid, ccount, clist, wT2);
}

// Round 6
// 180.340 us; speedup vs baseline: 1.1738x; 1.1738x over previous
//
#include <hip/hip_runtime.h>

// Problem constants (fixed by reference)
#define NB     432               // grid blocks; co-resident by __launch_bounds__(256,2) (VGPR~40, LDS 8.3KB)
#define BATCH  2
#define CIN    64
#define COUT   128
#define GD     14                // padded grid dim (12 + 2 halo)
#define GD2    (GD*GD)           // 196
#define NCELL  (GD*GD*GD)        // 2744
#define M      4096              // BATCH*NPTS
#define DCELL  1728              // 12^3 dense cells per batch
#define MAXP   16                // max tracked points/cell (lambda=1.19; P(>16) ~ 1e-11)

typedef __bf16 bf16x8 __attribute__((ext_vector_type(8)));
typedef float  f32x4  __attribute__((ext_vector_type(4)));
typedef unsigned short us8 __attribute__((ext_vector_type(8)));

__device__ __forceinline__ unsigned short bfc(float f) {
    return __builtin_bit_cast(unsigned short, (__bf16)f);   // RNE f32->bf16
}

// Persistent epoch counter. Zero at module load; never reset. Each launch adds exactly
// 2*NB, so "next multiple of NB" stays aligned across graph replays (same work every call).
__device__ int g_cnt;

// Grid barrier. KEY FIX vs R5: poll with RELAXED ordering (scope, not ordering, sets the
// coherent-read cache bits on CDNA) -> no buffer_inv per poll. Single fence after exit.
__device__ __forceinline__ void grid_barrier(int tid) {
    __syncthreads();          // drains this block's outstanding stores to L2
    if (tid == 0) {
        __threadfence();      // release: write back dirty lines to the coherent point
        int old = __hip_atomic_fetch_add(&g_cnt, 1, __ATOMIC_RELAXED, __HIP_MEMORY_SCOPE_AGENT);
        int target = (old / NB + 1) * NB;
        while (__hip_atomic_load(&g_cnt, __ATOMIC_RELAXED, __HIP_MEMORY_SCOPE_AGENT) < target)
            __builtin_amdgcn_s_sleep(8);
        __threadfence();      // acquire: invalidate stale lines ONCE after the epoch flips
    }
    __syncthreads();
}

// ONE kernel: zero+transpose | barrier | scatter+bucket | barrier | conv -> out
__global__ __launch_bounds__(256, 2) void k_all(const float* __restrict__ points,
                                                const float* __restrict__ features,
                                                const float* __restrict__ weight,
                                                const float* __restrict__ bias,
                                                float* __restrict__ out,
                                                float* __restrict__ voxgrid,
                                                int* __restrict__ ccount,
                                                int* __restrict__ clist,
                                                unsigned short* __restrict__ wT2) {
    const int t   = threadIdx.x;
    const int bid = blockIdx.x;
    __shared__ unsigned short lds[64*65];    // 8,320 B transpose tile

    // ---- phase 0a: zero voxgrid+ccount (contiguous: 354,688 dwords = 88,672 float4) ----
    {
        const int i = bid*256 + t;           // 110,592 threads cover 88,672 slots
        if (i < 88672) ((float4*)voxgrid)[i] = make_float4(0.f, 0.f, 0.f, 0.f);
    }
    // ---- phase 0b: blocks 0..53 transpose weight -> bf16 wT2[p][n][kk=ok*64+k] ----
    // block handles (p = bid/6, nh = (bid%6)/3, kt = bid%3): 64 n x 64 k elements
    if (bid < 54) {
        const int p  = bid / 6;
        const int rm = bid % 6;
        const int nh = rm / 3;
        const int kt = rm % 3;
        #pragma unroll
        for (int i2 = 0; i2 < 16; ++i2) {    // load coalesced over n (64 consecutive floats)
            const int s  = t + i2*256;       // [0,4096)
            const int nn = s & 63;
            const int kl = s >> 6;           // 0..63
            lds[nn*65 + kl] = bfc(weight[(p*3 + kt)*8192 + kl*128 + nh*64 + nn]);
        }
        __syncthreads();
        #pragma unroll
        for (int i2 = 0; i2 < 16; ++i2) {    // store coalesced over k (64 consecutive ushorts)
            const int s  = t + i2*256;
            const int nn = s >> 6;
            const int kl = s & 63;
            wT2[(size_t)(p*128 + nh*64 + nn)*192 + kt*64 + kl] = lds[nn*65 + kl];
        }
    }

    grid_barrier(t);

    // ---- phase 1: scatter features into voxgrid + build per-cell point lists ----
    for (int u = bid; u < 1024; u += NB) {   // 1024 units of 256 threads = M*CIN
        const int idx = u*256 + t;
        const int g   = idx >> 6;            // wave-uniform point index
        const int cin = idx & 63;
        const int vx = (int)points[g*3 + 0];
        const int vy = (int)points[g*3 + 1];
        const int vz = (int)points[g*3 + 2];
        const int b  = g >> 11;
        atomicAdd(&voxgrid[((size_t)b*NCELL + (vx+1)*GD2 + (vy+1)*GD + (vz+1))*CIN + cin],
                  features[idx]);
        if (cin == 0) {
            const int mg   = b*DCELL + vx*144 + vy*12 + vz;
            const int slot = atomicAdd(&ccount[mg], 1);
            if (slot < MAXP) clist[mg*MAXP + slot] = g;
        }
    }

    grid_barrier(t);

    // ---- phase 2: dense MFMA conv over 12^3, rows scattered straight to out ----
    // DOFF[p] = ((oi-1)*GD2 + (oj-1)*GD - 1) * 64 for p = oi*3+oj (contiguous 192-ch span)
    static constexpr int DOFF[9] = { -13504, -12608, -11712,
                                       -960,    -64,    832,
                                      11584,  12480,  13376 };
    const int l   = t & 63;
    const int w   = t >> 6;
    const int q   = l >> 4;                  // k-group / C-row quad
    const int col = l & 15;                  // A m-row and B n-col lane index
    const int mt  = bid >> 1;                // 0..215 m-tile
    const int nh  = bid & 1;
    const int b2  = (mt >= 108);
    const int cil = (mt - b2*108) * 16;
    const int n0  = nh*64 + w*16;

    const int ci = cil + col;
    const int cx = ci/144, cy = (ci/12)%12, cz = ci%12;
    const float* aptr = voxgrid + ((size_t)b2*NCELL + (cx+1)*GD2 + (cy+1)*GD + (cz+1))*CIN + q*8;
    const unsigned short* bptr = wT2 + (size_t)(n0 + col)*192 + q*8;

    f32x4 acc = {0.f, 0.f, 0.f, 0.f};
    float4 A0[4], A1[4]; us8 B0[4];
    #pragma unroll
    for (int st = 0; st < 4; ++st) {         // prolog: panel 0, k-steps 0..3
        A0[st] = *(const float4*)(aptr + DOFF[0] + st*32);
        A1[st] = *(const float4*)(aptr + DOFF[0] + st*32 + 4);
        B0[st] = *(const us8*)(bptr + st*32);
    }
    #pragma unroll
    for (int st = 0; st < 54; ++st) {        // 9 panels x 6 k-steps of 32
        const int sl = st & 3;
        const float4 xa = A0[sl], xb = A1[sl];
        const us8 bb = B0[sl];
        if (st + 4 < 54) {
            const int p = (st + 4) / 6, s = (st + 4) % 6;
            A0[sl] = *(const float4*)(aptr + DOFF[p] + s*32);
            A1[sl] = *(const float4*)(aptr + DOFF[p] + s*32 + 4);
            B0[sl] = *(const us8*)(bptr + p*24576 + s*32);
        }
        us8 a;
        a[0]=bfc(xa.x); a[1]=bfc(xa.y); a[2]=bfc(xa.z); a[3]=bfc(xa.w);
        a[4]=bfc(xb.x); a[5]=bfc(xb.y); a[6]=bfc(xb.z); a[7]=bfc(xb.w);
        acc = __builtin_amdgcn_mfma_f32_16x16x32_bf16(
                  __builtin_bit_cast(bf16x8, a), __builtin_bit_cast(bf16x8, bb), acc, 0, 0, 0);
    }

    // epilogue: C row m = q*4+r (cell), col n (cout); write each point's row directly
    const float bs = bias[n0 + col];
    #pragma unroll
    for (int r = 0; r < 4; ++r) {
        const int cir = cil + q*4 + r;
        const int mg  = b2*DCELL + cir;
        const int cnt = min(ccount[mg], MAXP);
        for (int j = 0; j < cnt; ++j) {
            const int g = clist[mg*MAXP + j];
            out[(size_t)g*COUT + n0 + col] = acc[r] + bs;
        }
    }
}

extern "C" void kernel_launch(void* const* d_in, const int* in_sizes, int n_in,
                              void* d_out, int out_size, void* d_ws, size_t ws_size,
                              hipStream_t stream) {
    (void)in_sizes; (void)n_in; (void)out_size; (void)ws_size;
    const float* points   = (const float*)d_in[0];  // (2,2048,3)
    const float* features = (const float*)d_in[1];  // (2,2048,64)
    const float* weight   = (const float*)d_in[2];  // (3,3,3,64,128)
    const float* bias     = (const float*)d_in[3];  // (128,)
    float* out = (float*)d_out;                     // (2,2048,128)

    char* ws = (char*)d_ws;
    float*          voxgrid = (float*)ws;                        // 1,404,928 B (zeroed in-kernel)
    int*            ccount  = (int*)(ws + 1404928);              //    13,824 B (contiguous w/ voxgrid zero)
    int*            clist   = (int*)(ws + 1418752);              //   221,184 B (guarded by ccount)
    unsigned short* wT2     = (unsigned short*)(ws + 1639936);   //   442,368 B

    k_all<<<NB, 256, 0, stream>>>(points, features, weight, bias, out,
                                  voxgrid, ccount, clist, wT2);
}